// Round 5
// baseline (120.128 us; speedup 1.0000x reference)
//
#include <hip/hip_runtime.h>
#include <math.h>

typedef __attribute__((ext_vector_type(8))) short bf16x8;
typedef __attribute__((ext_vector_type(8))) unsigned short u16x8;
typedef __attribute__((ext_vector_type(4))) float f32x4;

__device__ __forceinline__ unsigned short f2bf(float f) {
  unsigned u = __float_as_uint(f);
  return (unsigned short)((u + 0x7FFFu + ((u >> 16) & 1u)) >> 16);
}
__device__ __forceinline__ float bf2f(unsigned short h) {
  return __uint_as_float(((unsigned)h) << 16);
}
// split fp32x8 -> bf16 hi + bf16 lo residual, directly as MFMA operands
__device__ __forceinline__ void cvt8b(const float4& a, const float4& b,
                                      bf16x8& h, bf16x8& l) {
  float f[8] = {a.x, a.y, a.z, a.w, b.x, b.y, b.z, b.w};
#pragma unroll
  for (int i = 0; i < 8; ++i) {
    unsigned short hh = f2bf(f[i]);
    h[i] = (short)hh;
    l[i] = (short)f2bf(f[i] - bf2f(hh));
  }
}

// pair tables: 36 (m,n) pairs with m<=n
__device__ const int PM36[36] = {0,0,0,0,0,0,0,0, 1,1,1,1,1,1,1, 2,2,2,2,2,2,
                                 3,3,3,3,3, 4,4,4,4, 5,5,5, 6,6, 7};
__device__ const int PN36[36] = {0,1,2,3,4,5,6,7, 1,2,3,4,5,6,7, 2,3,4,5,6,7,
                                 3,4,5,6,7, 4,5,6,7, 5,6,7, 6,7, 7};
__device__ __forceinline__ constexpr int gidx(int a, int b) {
  int m = a < b ? a : b, n = a < b ? b : a;
  return m * 8 - (m * (m - 1)) / 2 + (n - m);
}

// ---------------------------------------------------------------------------
// K0 (merged): blocks 0-15: split/transpose Wp -> th1/tl1 [kt16][kg8][col128][e8]
//              blocks 16-31: split Wflat -> th2/tl2 [kt2][kg8][col512][e8]
//              blocks 32-95: Gram M[a][b] = Wf[a]·Wf[b]
// ---------------------------------------------------------------------------
__global__ __launch_bounds__(256) void caps_prep_all(
    const float* __restrict__ Wp, const float* __restrict__ W,
    unsigned short* __restrict__ th1, unsigned short* __restrict__ tl1,
    unsigned short* __restrict__ th2, unsigned short* __restrict__ tl2,
    float* __restrict__ M)
{
  __shared__ float tile[64][128];
  const int t = threadIdx.x, b = blockIdx.x;
  if (b < 16) {
    const float* src = Wp + (size_t)b * 64 * 128;
#pragma unroll
    for (int i = 0; i < 8; ++i) {
      int j = t + i * 256;
      int kk = j >> 5, q = j & 31;
      *(float4*)&tile[kk][q * 4] = *(const float4*)(src + kk * 128 + q * 4);
    }
    __syncthreads();
    const int col = t >> 1, kg0 = (t & 1) * 4;
    unsigned short hi[32], lo[32];
#pragma unroll
    for (int kk = 0; kk < 32; ++kk) {
      float v = tile[kg0 * 8 + kk][col];
      unsigned short h = f2bf(v);
      hi[kk] = h;
      lo[kk] = f2bf(v - bf2f(h));
    }
#pragma unroll
    for (int i = 0; i < 4; ++i) {
      size_t off = (size_t)b * 8192 + (size_t)(kg0 + i) * 1024 + (size_t)col * 8;
      u16x8 vh, vl;
#pragma unroll
      for (int e = 0; e < 8; ++e) { vh[e] = hi[i * 8 + e]; vl[e] = lo[i * 8 + e]; }
      *(u16x8*)(th1 + off) = vh;
      *(u16x8*)(tl1 + off) = vl;
    }
  } else if (b < 32) {
    int tt = (b - 16) * 256 + t;
#pragma unroll
    for (int h = 0; h < 2; ++h) {
      int c = tt + h * 4096;
      int kt = c >> 12, rem = c & 4095;
      int kg = rem >> 9, col = rem & 511;
      int kbase = kt * 64 + kg * 8;
      u16x8 vh, vl;
#pragma unroll
      for (int e = 0; e < 8; ++e) {
        float v = W[(size_t)(kbase + e) * 512 + col];
        unsigned short hh = f2bf(v);
        vh[e] = hh;
        vl[e] = f2bf(v - bf2f(hh));
      }
      size_t off = ((size_t)(kt * 8 + kg) * 512 + col) * 8;
      *(u16x8*)(th2 + off) = vh;
      *(u16x8*)(tl2 + off) = vl;
    }
  } else {
    int bb = b - 32;
    int a = (bb >> 3) * 16 + (t >> 4);
    int c = (bb & 7) * 16 + (t & 15);
    const float* wa = W + (size_t)a * 512;
    const float* wb = W + (size_t)c * 512;
    float acc = 0.f;
#pragma unroll 4
    for (int o = 0; o < 512; o += 4) {
      float4 xx = *(const float4*)(wa + o);
      float4 yy = *(const float4*)(wb + o);
      acc += xx.x * yy.x + xx.y * yy.y + xx.z * yy.z + xx.w * yy.w;
    }
    M[a * 128 + c] = acc;
  }
}

// ---------------------------------------------------------------------------
// K1: p = squash(x @ Wp + bp), split-bf16 MFMA, fully LDS-free / barrier-free.
// Grid 512 x 256 thr (4 waves). Wave: 16 rows x 64 cols.
//   wave w: rowg=w>>1 (rows blk*32+rowg*16+..), ch=w&1 (cols ch*64+..)
//   lane: cb=lane&15 (row for A / col for B), kgl=lane>>4 (k-group)
// A fragments loaded directly from x (k-contiguous), B from pre-split tiles.
// ---------------------------------------------------------------------------
__global__ __launch_bounds__(256) void caps_primary(
    const float* __restrict__ x, const unsigned short* __restrict__ bth,
    const unsigned short* __restrict__ btl, const float* __restrict__ bp,
    float* __restrict__ p_out)
{
  const int tid = threadIdx.x, lane = tid & 63, w = tid >> 6;
  const int rowg = w >> 1, ch = w & 1;
  const int cb = lane & 15, kgl = lane >> 4;
  const int rA = blockIdx.x * 32 + rowg * 16 + cb;
  const float* xp = x + (size_t)rA * 1024;
  const bf16x8* Bh = (const bf16x8*)bth;   // fragment units (8 ushorts)
  const bf16x8* Bl = (const bf16x8*)btl;
  const int bb0 = kgl * 128 + ch * 64 + cb;

  f32x4 acc[4];
#pragma unroll
  for (int j = 0; j < 4; ++j) acc[j] = (f32x4){0.f, 0.f, 0.f, 0.f};

#pragma unroll 2
  for (int kt = 0; kt < 16; ++kt) {
    const float* xk = xp + kt * 64 + kgl * 8;
    float4 a00 = *(const float4*)(xk);
    float4 a01 = *(const float4*)(xk + 4);
    float4 a10 = *(const float4*)(xk + 32);
    float4 a11 = *(const float4*)(xk + 36);
    bf16x8 ah0, al0, ah1, al1;
    cvt8b(a00, a01, ah0, al0);
    cvt8b(a10, a11, ah1, al1);
    const int kb = bb0 + kt * 1024;
#pragma unroll
    for (int nf = 0; nf < 4; ++nf) {
      bf16x8 bh0 = Bh[kb + nf * 16];
      bf16x8 bl0 = Bl[kb + nf * 16];
      bf16x8 bh1 = Bh[kb + 512 + nf * 16];
      bf16x8 bl1 = Bl[kb + 512 + nf * 16];
      acc[nf] = __builtin_amdgcn_mfma_f32_16x16x32_bf16(ah0, bh0, acc[nf], 0, 0, 0);
      acc[nf] = __builtin_amdgcn_mfma_f32_16x16x32_bf16(ah0, bl0, acc[nf], 0, 0, 0);
      acc[nf] = __builtin_amdgcn_mfma_f32_16x16x32_bf16(al0, bh0, acc[nf], 0, 0, 0);
      acc[nf] = __builtin_amdgcn_mfma_f32_16x16x32_bf16(ah1, bh1, acc[nf], 0, 0, 0);
      acc[nf] = __builtin_amdgcn_mfma_f32_16x16x32_bf16(ah1, bl1, acc[nf], 0, 0, 0);
      acc[nf] = __builtin_amdgcn_mfma_f32_16x16x32_bf16(al1, bh1, acc[nf], 0, 0, 0);
    }
  }

  // bias + per-capsule squash; C/D: row=(lane>>4)*4+r, col=lane&15 per nf
  const int l4 = lane >> 4;
#pragma unroll
  for (int nf = 0; nf < 4; ++nf) {
    float bpv = bp[ch * 64 + nf * 16 + cb];
#pragma unroll
    for (int r = 0; r < 4; ++r) {
      float val = acc[nf][r] + bpv;
      float sq = val * val;
      sq += __shfl_xor(sq, 1); sq += __shfl_xor(sq, 2);
      sq += __shfl_xor(sq, 4); sq += __shfl_xor(sq, 8);
      float sc = (sq / (1.f + sq)) / sqrtf(sq + 1e-8f);
      p_out[(size_t)(blockIdx.x * 32 + rowg * 16 + l4 * 4 + r) * 128 +
            ch * 64 + nf * 16 + cb] = val * sc;
    }
  }
}

// ---------------------------------------------------------------------------
// K2: Gram-based routing (verified round 4, unchanged).
// ---------------------------------------------------------------------------
__global__ __launch_bounds__(256, 1) void caps_route_g(
    const float* __restrict__ p_in, const float* __restrict__ Mg,
    float* __restrict__ qout)
{
  __shared__ float p_lds[128 * 66];
  __shared__ float M_lds[16384];
  __shared__ float G_lds[64 * 37];
  __shared__ float cs_lds[64 * 9];
  const int tid  = threadIdx.x;
  const int lane = tid & 63;
  const int w    = tid >> 6;
  const int row0 = blockIdx.x * 64;

#pragma unroll
  for (int i = 0; i < 8; ++i) {
    int j = tid + i * 256;
    int r = j >> 5, c4 = j & 31;
    float4 v = *(const float4*)(p_in + (size_t)(row0 + r) * 128 + c4 * 4);
    p_lds[(c4 * 4 + 0) * 66 + r] = v.x;
    p_lds[(c4 * 4 + 1) * 66 + r] = v.y;
    p_lds[(c4 * 4 + 2) * 66 + r] = v.z;
    p_lds[(c4 * 4 + 3) * 66 + r] = v.w;
  }
#pragma unroll
  for (int i = 0; i < 16; ++i) {
    int j = tid + i * 256;
    *(float4*)&M_lds[j * 4] = *(const float4*)(Mg + j * 4);
  }
  __syncthreads();

  for (int i = 0; i < 9; ++i) {
    const int pi = w * 9 + i;
    const int m = PM36[pi], n = PN36[pi];
    float pm[16], pn[16];
#pragma unroll
    for (int j = 0; j < 16; ++j) pm[j] = p_lds[(m * 16 + j) * 66 + lane];
#pragma unroll
    for (int j = 0; j < 16; ++j) pn[j] = p_lds[(n * 16 + j) * 66 + lane];
    float acc = 0.f;
#pragma unroll
    for (int ii = 0; ii < 16; ++ii) {
      const float* Mr = &M_lds[(n * 16 + ii) * 128 + m * 16];
      float t = 0.f;
#pragma unroll
      for (int j4 = 0; j4 < 4; ++j4) {
        float4 mv = *(const float4*)(Mr + j4 * 4);
        t = fmaf(mv.x, pm[j4 * 4 + 0], t);
        t = fmaf(mv.y, pm[j4 * 4 + 1], t);
        t = fmaf(mv.z, pm[j4 * 4 + 2], t);
        t = fmaf(mv.w, pm[j4 * 4 + 3], t);
      }
      acc = fmaf(pn[ii], t, acc);
    }
    G_lds[lane * 37 + pi] = acc;
  }
  __syncthreads();

  if (w == 0) {
    float Gf[36];
#pragma unroll
    for (int j = 0; j < 36; ++j) Gf[j] = G_lds[lane * 37 + j];
    float bb[8] = {0.f, 0.f, 0.f, 0.f, 0.f, 0.f, 0.f, 0.f};
    float cs[8];
#pragma unroll
    for (int it = 0; it < 3; ++it) {
      float mx = bb[0];
#pragma unroll
      for (int n = 1; n < 8; ++n) mx = fmaxf(mx, bb[n]);
      float e[8], Z = 0.f;
#pragma unroll
      for (int n = 0; n < 8; ++n) { e[n] = expf(bb[n] - mx); Z += e[n]; }
      float inv = 1.f / Z;
      float c[8];
#pragma unroll
      for (int n = 0; n < 8; ++n) c[n] = e[n] * inv;
      float t[8] = {0.f, 0.f, 0.f, 0.f, 0.f, 0.f, 0.f, 0.f};
#pragma unroll
      for (int n = 0; n < 8; ++n)
#pragma unroll
        for (int m2 = 0; m2 < 8; ++m2)
          t[n] = fmaf(Gf[gidx(n, m2)], c[m2], t[n]);
      float ss = 0.f;
#pragma unroll
      for (int n = 0; n < 8; ++n) ss = fmaf(c[n], t[n], ss);
      float scale = (ss / (1.f + ss)) / sqrtf(ss + 1e-8f);
      if (it < 2) {
#pragma unroll
        for (int n = 0; n < 8; ++n) bb[n] += scale * t[n];
      } else {
#pragma unroll
        for (int n = 0; n < 8; ++n) cs[n] = scale * c[n];
      }
    }
#pragma unroll
    for (int n = 0; n < 8; ++n) cs_lds[lane * 9 + n] = cs[n];
  }
  __syncthreads();

#pragma unroll
  for (int i = 0; i < 8; ++i) {
    int j = tid + i * 256;
    int r = j >> 5, c4 = j & 31;
    float4 pv = *(const float4*)(p_in + (size_t)(row0 + r) * 128 + c4 * 4);
    float csv = cs_lds[r * 9 + (c4 >> 2)];
    *(float4*)(qout + (size_t)(row0 + r) * 128 + c4 * 4) =
        make_float4(pv.x * csv, pv.y * csv, pv.z * csv, pv.w * csv);
  }
}

// ---------------------------------------------------------------------------
// K3: v = q @ Wflat  [16384,128]x[128,512] split-bf16 MFMA.
// A register-direct from q; B staged ONCE to 64 KB LDS (1 barrier).
// Block 512 thr (8 waves: 4 wm x 2 wn), BM=64, BN=128, grid (256,4).
// ---------------------------------------------------------------------------
__global__ __launch_bounds__(512) void caps_vout(
    const float* __restrict__ q, const unsigned short* __restrict__ bth,
    const unsigned short* __restrict__ btl, float* __restrict__ out)
{
  __shared__ unsigned short Bsh[32768];   // hi @0, lo @16384 (ushorts)
  const int tid  = threadIdx.x;
  const int lane = tid & 63;
  const int w    = tid >> 6;
  const int wm   = w >> 1;
  const int wn   = w & 1;
  const int row0 = blockIdx.x * 64;
  const int col0 = blockIdx.y * 128;

  // stage both K-tiles of B for this col-slab: [kt2][kg8][128col][e8]
#pragma unroll
  for (int i = 0; i < 4; ++i) {
    int idx = tid + i * 512;               // 2048 chunks
    int kt = idx >> 10, kg = (idx >> 7) & 7, col = idx & 127;
    size_t g = ((size_t)(kt * 8 + kg) * 512 + col0 + col) * 8;
    *(u16x8*)&Bsh[idx * 8] = *(const u16x8*)(bth + g);
    *(u16x8*)&Bsh[16384 + idx * 8] = *(const u16x8*)(btl + g);
  }
  __syncthreads();

  const int cb = lane & 15, kgl = lane >> 4;
  const int rA = row0 + wm * 16 + cb;
  const float* qp = q + (size_t)rA * 128;

  f32x4 acc[4];
#pragma unroll
  for (int j = 0; j < 4; ++j) acc[j] = (f32x4){0.f, 0.f, 0.f, 0.f};

#pragma unroll
  for (int kt = 0; kt < 2; ++kt) {
    const float* qk = qp + kt * 64 + kgl * 8;
    float4 a00 = *(const float4*)(qk);
    float4 a01 = *(const float4*)(qk + 4);
    float4 a10 = *(const float4*)(qk + 32);
    float4 a11 = *(const float4*)(qk + 36);
    bf16x8 ah0, al0, ah1, al1;
    cvt8b(a00, a01, ah0, al0);
    cvt8b(a10, a11, ah1, al1);
#pragma unroll
    for (int nf = 0; nf < 4; ++nf) {
      int c = wn * 64 + nf * 16 + cb;
      int i0 = ((kt * 8 + kgl) * 128 + c) * 8;
      int i1 = ((kt * 8 + 4 + kgl) * 128 + c) * 8;
      bf16x8 bh0 = *(const bf16x8*)&Bsh[i0];
      bf16x8 bl0 = *(const bf16x8*)&Bsh[16384 + i0];
      bf16x8 bh1 = *(const bf16x8*)&Bsh[i1];
      bf16x8 bl1 = *(const bf16x8*)&Bsh[16384 + i1];
      acc[nf] = __builtin_amdgcn_mfma_f32_16x16x32_bf16(ah0, bh0, acc[nf], 0, 0, 0);
      acc[nf] = __builtin_amdgcn_mfma_f32_16x16x32_bf16(ah0, bl0, acc[nf], 0, 0, 0);
      acc[nf] = __builtin_amdgcn_mfma_f32_16x16x32_bf16(al0, bh0, acc[nf], 0, 0, 0);
      acc[nf] = __builtin_amdgcn_mfma_f32_16x16x32_bf16(ah1, bh1, acc[nf], 0, 0, 0);
      acc[nf] = __builtin_amdgcn_mfma_f32_16x16x32_bf16(ah1, bl1, acc[nf], 0, 0, 0);
      acc[nf] = __builtin_amdgcn_mfma_f32_16x16x32_bf16(al1, bh1, acc[nf], 0, 0, 0);
    }
  }

  const int l4 = lane >> 4;
#pragma unroll
  for (int nf = 0; nf < 4; ++nf)
#pragma unroll
    for (int r = 0; r < 4; ++r)
      out[(size_t)(row0 + wm * 16 + l4 * 4 + r) * 512 +
          col0 + wn * 64 + nf * 16 + cb] = acc[nf][r];
}

extern "C" void kernel_launch(void* const* d_in, const int* in_sizes, int n_in,
                              void* d_out, int out_size, void* d_ws, size_t ws_size,
                              hipStream_t stream) {
  (void)in_sizes; (void)n_in; (void)out_size; (void)ws_size;
  const float* x  = (const float*)d_in[0];
  const float* Wp = (const float*)d_in[1];
  const float* bp = (const float*)d_in[2];
  const float* W  = (const float*)d_in[3];
  // d_in[4] = n_routing (fixed = 3)
  char* ws = (char*)d_ws;
  float* p_ws = (float*)ws;                                   // 8 MB (p, then q in-place)
  unsigned short* th1 = (unsigned short*)(ws + 8388608);      // 256 KB
  unsigned short* tl1 = (unsigned short*)(ws + 8650752);      // 256 KB
  unsigned short* th2 = (unsigned short*)(ws + 8912896);      // 128 KB
  unsigned short* tl2 = (unsigned short*)(ws + 9043968);      // 128 KB
  float* Mws = (float*)(ws + 9175040);                        // 64 KB
  float* outp = (float*)d_out;

  caps_prep_all<<<96, 256, 0, stream>>>(Wp, W, th1, tl1, th2, tl2, Mws);
  caps_primary<<<512, 256, 0, stream>>>(x, th1, tl1, bp, p_ws);
  caps_route_g<<<256, 256, 0, stream>>>(p_ws, Mws, p_ws);
  caps_vout<<<dim3(256, 4), 512, 0, stream>>>(p_ws, th2, tl2, outp);
}

// Round 6
// 117.507 us; speedup vs baseline: 1.0223x; 1.0223x over previous
//
#include <hip/hip_runtime.h>
#include <math.h>

typedef __attribute__((ext_vector_type(8))) short bf16x8;
typedef __attribute__((ext_vector_type(8))) unsigned short u16x8;
typedef __attribute__((ext_vector_type(4))) float f32x4;

__device__ __forceinline__ unsigned short f2bf(float f) {
  unsigned u = __float_as_uint(f);
  return (unsigned short)((u + 0x7FFFu + ((u >> 16) & 1u)) >> 16);
}
__device__ __forceinline__ float bf2f(unsigned short h) {
  return __uint_as_float(((unsigned)h) << 16);
}
// split fp32x8 -> bf16 hi + bf16 lo residual, directly as MFMA operands
__device__ __forceinline__ void cvt8b(const float4& a, const float4& b,
                                      bf16x8& h, bf16x8& l) {
  float f[8] = {a.x, a.y, a.z, a.w, b.x, b.y, b.z, b.w};
#pragma unroll
  for (int i = 0; i < 8; ++i) {
    unsigned short hh = f2bf(f[i]);
    h[i] = (short)hh;
    l[i] = (short)f2bf(f[i] - bf2f(hh));
  }
}

// pair tables: 36 (m,n) pairs with m<=n
__device__ const int PM36[36] = {0,0,0,0,0,0,0,0, 1,1,1,1,1,1,1, 2,2,2,2,2,2,
                                 3,3,3,3,3, 4,4,4,4, 5,5,5, 6,6, 7};
__device__ const int PN36[36] = {0,1,2,3,4,5,6,7, 1,2,3,4,5,6,7, 2,3,4,5,6,7,
                                 3,4,5,6,7, 4,5,6,7, 5,6,7, 6,7, 7};
__device__ __forceinline__ constexpr int gidx(int a, int b) {
  int m = a < b ? a : b, n = a < b ? b : a;
  return m * 8 - (m * (m - 1)) / 2 + (n - m);
}

// ---------------------------------------------------------------------------
// K0 (merged): blocks 0-15: split/transpose Wp -> th1/tl1 [kt16][kg8][col128][e8]
//              blocks 16-31: split Wflat -> th2/tl2 [kt2][kg8][col512][e8]
//              blocks 32-95: Gram M[a][b] = Wf[a]·Wf[b]
// ---------------------------------------------------------------------------
__global__ __launch_bounds__(256) void caps_prep_all(
    const float* __restrict__ Wp, const float* __restrict__ W,
    unsigned short* __restrict__ th1, unsigned short* __restrict__ tl1,
    unsigned short* __restrict__ th2, unsigned short* __restrict__ tl2,
    float* __restrict__ M)
{
  __shared__ float tile[64][128];
  const int t = threadIdx.x, b = blockIdx.x;
  if (b < 16) {
    const float* src = Wp + (size_t)b * 64 * 128;
#pragma unroll
    for (int i = 0; i < 8; ++i) {
      int j = t + i * 256;
      int kk = j >> 5, q = j & 31;
      *(float4*)&tile[kk][q * 4] = *(const float4*)(src + kk * 128 + q * 4);
    }
    __syncthreads();
    const int col = t >> 1, kg0 = (t & 1) * 4;
    unsigned short hi[32], lo[32];
#pragma unroll
    for (int kk = 0; kk < 32; ++kk) {
      float v = tile[kg0 * 8 + kk][col];
      unsigned short h = f2bf(v);
      hi[kk] = h;
      lo[kk] = f2bf(v - bf2f(h));
    }
#pragma unroll
    for (int i = 0; i < 4; ++i) {
      size_t off = (size_t)b * 8192 + (size_t)(kg0 + i) * 1024 + (size_t)col * 8;
      u16x8 vh, vl;
#pragma unroll
      for (int e = 0; e < 8; ++e) { vh[e] = hi[i * 8 + e]; vl[e] = lo[i * 8 + e]; }
      *(u16x8*)(th1 + off) = vh;
      *(u16x8*)(tl1 + off) = vl;
    }
  } else if (b < 32) {
    int tt = (b - 16) * 256 + t;
#pragma unroll
    for (int h = 0; h < 2; ++h) {
      int c = tt + h * 4096;
      int kt = c >> 12, rem = c & 4095;
      int kg = rem >> 9, col = rem & 511;
      int kbase = kt * 64 + kg * 8;
      u16x8 vh, vl;
#pragma unroll
      for (int e = 0; e < 8; ++e) {
        float v = W[(size_t)(kbase + e) * 512 + col];
        unsigned short hh = f2bf(v);
        vh[e] = hh;
        vl[e] = f2bf(v - bf2f(hh));
      }
      size_t off = ((size_t)(kt * 8 + kg) * 512 + col) * 8;
      *(u16x8*)(th2 + off) = vh;
      *(u16x8*)(tl2 + off) = vl;
    }
  } else {
    int bb = b - 32;
    int a = (bb >> 3) * 16 + (t >> 4);
    int c = (bb & 7) * 16 + (t & 15);
    const float* wa = W + (size_t)a * 512;
    const float* wb = W + (size_t)c * 512;
    float acc = 0.f;
#pragma unroll 4
    for (int o = 0; o < 512; o += 4) {
      float4 xx = *(const float4*)(wa + o);
      float4 yy = *(const float4*)(wb + o);
      acc += xx.x * yy.x + xx.y * yy.y + xx.z * yy.z + xx.w * yy.w;
    }
    M[a * 128 + c] = acc;
  }
}

// ---------------------------------------------------------------------------
// K1: p = squash(x @ Wp + bp), split-bf16 MFMA, LDS-free, explicit depth-1
// register double-buffer: all of kt+1's loads issued before kt's compute.
// Grid 512 x 256 thr (4 waves). Wave: 16 rows x 64 cols.
// ---------------------------------------------------------------------------
__global__ __launch_bounds__(256, 2) void caps_primary(
    const float* __restrict__ x, const unsigned short* __restrict__ bth,
    const unsigned short* __restrict__ btl, const float* __restrict__ bp,
    float* __restrict__ p_out)
{
  const int tid = threadIdx.x, lane = tid & 63, w = tid >> 6;
  const int rowg = w >> 1, ch = w & 1;
  const int cb = lane & 15, kgl = lane >> 4;
  const int rA = blockIdx.x * 32 + rowg * 16 + cb;
  const float* xp = x + (size_t)rA * 1024;
  const bf16x8* Bh = (const bf16x8*)bth;   // fragment units (8 ushorts)
  const bf16x8* Bl = (const bf16x8*)btl;
  const int bb0 = kgl * 128 + ch * 64 + cb;

  f32x4 acc[4];
#pragma unroll
  for (int j = 0; j < 4; ++j) acc[j] = (f32x4){0.f, 0.f, 0.f, 0.f};

#define LOADX(kt, X) do { const float* xk = xp + (kt) * 64 + kgl * 8; \
    X[0] = *(const float4*)(xk);      X[1] = *(const float4*)(xk + 4); \
    X[2] = *(const float4*)(xk + 32); X[3] = *(const float4*)(xk + 36); } while (0)

#define LOADB(kt, BH, BL) do { const int kb_ = bb0 + (kt) * 1024; \
    _Pragma("unroll") for (int nf = 0; nf < 4; ++nf) { \
      BH[nf]     = Bh[kb_ + nf * 16]; \
      BH[4 + nf] = Bh[kb_ + 512 + nf * 16]; \
      BL[nf]     = Bl[kb_ + nf * 16]; \
      BL[4 + nf] = Bl[kb_ + 512 + nf * 16]; } } while (0)

#define STEP(X, BH, BL) do { bf16x8 ah0, al0, ah1, al1; \
    cvt8b(X[0], X[1], ah0, al0); cvt8b(X[2], X[3], ah1, al1); \
    _Pragma("unroll") for (int nf = 0; nf < 4; ++nf) { \
      acc[nf] = __builtin_amdgcn_mfma_f32_16x16x32_bf16(ah0, BH[nf], acc[nf], 0, 0, 0); \
      acc[nf] = __builtin_amdgcn_mfma_f32_16x16x32_bf16(ah0, BL[nf], acc[nf], 0, 0, 0); \
      acc[nf] = __builtin_amdgcn_mfma_f32_16x16x32_bf16(al0, BH[nf], acc[nf], 0, 0, 0); \
      acc[nf] = __builtin_amdgcn_mfma_f32_16x16x32_bf16(ah1, BH[4 + nf], acc[nf], 0, 0, 0); \
      acc[nf] = __builtin_amdgcn_mfma_f32_16x16x32_bf16(ah1, BL[4 + nf], acc[nf], 0, 0, 0); \
      acc[nf] = __builtin_amdgcn_mfma_f32_16x16x32_bf16(al1, BH[4 + nf], acc[nf], 0, 0, 0); } } while (0)

  float4 X0[4], X1[4];
  bf16x8 BH0[8], BL0[8], BH1[8], BL1[8];

  LOADX(0, X0);
  LOADB(0, BH0, BL0);
#pragma unroll
  for (int kt = 0; kt < 16; kt += 2) {
    if (kt + 1 < 16) { LOADX(kt + 1, X1); LOADB(kt + 1, BH1, BL1); }
    STEP(X0, BH0, BL0);
    if (kt + 2 < 16) { LOADX(kt + 2, X0); LOADB(kt + 2, BH0, BL0); }
    if (kt + 1 < 16) STEP(X1, BH1, BL1);
  }
#undef LOADX
#undef LOADB
#undef STEP

  // bias + per-capsule squash; C/D: row=(lane>>4)*4+r, col=lane&15 per nf
  const int l4 = lane >> 4;
#pragma unroll
  for (int nf = 0; nf < 4; ++nf) {
    float bpv = bp[ch * 64 + nf * 16 + cb];
#pragma unroll
    for (int r = 0; r < 4; ++r) {
      float val = acc[nf][r] + bpv;
      float sq = val * val;
      sq += __shfl_xor(sq, 1); sq += __shfl_xor(sq, 2);
      sq += __shfl_xor(sq, 4); sq += __shfl_xor(sq, 8);
      float sc = (sq / (1.f + sq)) / sqrtf(sq + 1e-8f);
      p_out[(size_t)(blockIdx.x * 32 + rowg * 16 + l4 * 4 + r) * 128 +
            ch * 64 + nf * 16 + cb] = val * sc;
    }
  }
}

// ---------------------------------------------------------------------------
// K2: Gram-based routing (verified round 4, unchanged).
// ---------------------------------------------------------------------------
__global__ __launch_bounds__(256, 1) void caps_route_g(
    const float* __restrict__ p_in, const float* __restrict__ Mg,
    float* __restrict__ qout)
{
  __shared__ float p_lds[128 * 66];
  __shared__ float M_lds[16384];
  __shared__ float G_lds[64 * 37];
  __shared__ float cs_lds[64 * 9];
  const int tid  = threadIdx.x;
  const int lane = tid & 63;
  const int w    = tid >> 6;
  const int row0 = blockIdx.x * 64;

#pragma unroll
  for (int i = 0; i < 8; ++i) {
    int j = tid + i * 256;
    int r = j >> 5, c4 = j & 31;
    float4 v = *(const float4*)(p_in + (size_t)(row0 + r) * 128 + c4 * 4);
    p_lds[(c4 * 4 + 0) * 66 + r] = v.x;
    p_lds[(c4 * 4 + 1) * 66 + r] = v.y;
    p_lds[(c4 * 4 + 2) * 66 + r] = v.z;
    p_lds[(c4 * 4 + 3) * 66 + r] = v.w;
  }
#pragma unroll
  for (int i = 0; i < 16; ++i) {
    int j = tid + i * 256;
    *(float4*)&M_lds[j * 4] = *(const float4*)(Mg + j * 4);
  }
  __syncthreads();

  for (int i = 0; i < 9; ++i) {
    const int pi = w * 9 + i;
    const int m = PM36[pi], n = PN36[pi];
    float pm[16], pn[16];
#pragma unroll
    for (int j = 0; j < 16; ++j) pm[j] = p_lds[(m * 16 + j) * 66 + lane];
#pragma unroll
    for (int j = 0; j < 16; ++j) pn[j] = p_lds[(n * 16 + j) * 66 + lane];
    float acc = 0.f;
#pragma unroll
    for (int ii = 0; ii < 16; ++ii) {
      const float* Mr = &M_lds[(n * 16 + ii) * 128 + m * 16];
      float t = 0.f;
#pragma unroll
      for (int j4 = 0; j4 < 4; ++j4) {
        float4 mv = *(const float4*)(Mr + j4 * 4);
        t = fmaf(mv.x, pm[j4 * 4 + 0], t);
        t = fmaf(mv.y, pm[j4 * 4 + 1], t);
        t = fmaf(mv.z, pm[j4 * 4 + 2], t);
        t = fmaf(mv.w, pm[j4 * 4 + 3], t);
      }
      acc = fmaf(pn[ii], t, acc);
    }
    G_lds[lane * 37 + pi] = acc;
  }
  __syncthreads();

  if (w == 0) {
    float Gf[36];
#pragma unroll
    for (int j = 0; j < 36; ++j) Gf[j] = G_lds[lane * 37 + j];
    float bb[8] = {0.f, 0.f, 0.f, 0.f, 0.f, 0.f, 0.f, 0.f};
    float cs[8];
#pragma unroll
    for (int it = 0; it < 3; ++it) {
      float mx = bb[0];
#pragma unroll
      for (int n = 1; n < 8; ++n) mx = fmaxf(mx, bb[n]);
      float e[8], Z = 0.f;
#pragma unroll
      for (int n = 0; n < 8; ++n) { e[n] = expf(bb[n] - mx); Z += e[n]; }
      float inv = 1.f / Z;
      float c[8];
#pragma unroll
      for (int n = 0; n < 8; ++n) c[n] = e[n] * inv;
      float t[8] = {0.f, 0.f, 0.f, 0.f, 0.f, 0.f, 0.f, 0.f};
#pragma unroll
      for (int n = 0; n < 8; ++n)
#pragma unroll
        for (int m2 = 0; m2 < 8; ++m2)
          t[n] = fmaf(Gf[gidx(n, m2)], c[m2], t[n]);
      float ss = 0.f;
#pragma unroll
      for (int n = 0; n < 8; ++n) ss = fmaf(c[n], t[n], ss);
      float scale = (ss / (1.f + ss)) / sqrtf(ss + 1e-8f);
      if (it < 2) {
#pragma unroll
        for (int n = 0; n < 8; ++n) bb[n] += scale * t[n];
      } else {
#pragma unroll
        for (int n = 0; n < 8; ++n) cs[n] = scale * c[n];
      }
    }
#pragma unroll
    for (int n = 0; n < 8; ++n) cs_lds[lane * 9 + n] = cs[n];
  }
  __syncthreads();

#pragma unroll
  for (int i = 0; i < 8; ++i) {
    int j = tid + i * 256;
    int r = j >> 5, c4 = j & 31;
    float4 pv = *(const float4*)(p_in + (size_t)(row0 + r) * 128 + c4 * 4);
    float csv = cs_lds[r * 9 + (c4 >> 2)];
    *(float4*)(qout + (size_t)(row0 + r) * 128 + c4 * 4) =
        make_float4(pv.x * csv, pv.y * csv, pv.z * csv, pv.w * csv);
  }
}

// ---------------------------------------------------------------------------
// K3: v = q @ Wflat  [16384,128]x[128,512] split-bf16 MFMA.
// A register-direct from q; B staged ONCE to 64 KB LDS (1 barrier).
// Block 512 thr (8 waves: 4 wm x 2 wn), BM=64, BN=128, grid (256,4).
// ---------------------------------------------------------------------------
__global__ __launch_bounds__(512) void caps_vout(
    const float* __restrict__ q, const unsigned short* __restrict__ bth,
    const unsigned short* __restrict__ btl, float* __restrict__ out)
{
  __shared__ unsigned short Bsh[32768];   // hi @0, lo @16384 (ushorts)
  const int tid  = threadIdx.x;
  const int lane = tid & 63;
  const int w    = tid >> 6;
  const int wm   = w >> 1;
  const int wn   = w & 1;
  const int row0 = blockIdx.x * 64;
  const int col0 = blockIdx.y * 128;

  // stage both K-tiles of B for this col-slab: [kt2][kg8][128col][e8]
#pragma unroll
  for (int i = 0; i < 4; ++i) {
    int idx = tid + i * 512;               // 2048 chunks
    int kt = idx >> 10, kg = (idx >> 7) & 7, col = idx & 127;
    size_t g = ((size_t)(kt * 8 + kg) * 512 + col0 + col) * 8;
    *(u16x8*)&Bsh[idx * 8] = *(const u16x8*)(bth + g);
    *(u16x8*)&Bsh[16384 + idx * 8] = *(const u16x8*)(btl + g);
  }
  __syncthreads();

  const int cb = lane & 15, kgl = lane >> 4;
  const int rA = row0 + wm * 16 + cb;
  const float* qp = q + (size_t)rA * 128;

  f32x4 acc[4];
#pragma unroll
  for (int j = 0; j < 4; ++j) acc[j] = (f32x4){0.f, 0.f, 0.f, 0.f};

#pragma unroll
  for (int kt = 0; kt < 2; ++kt) {
    const float* qk = qp + kt * 64 + kgl * 8;
    float4 a00 = *(const float4*)(qk);
    float4 a01 = *(const float4*)(qk + 4);
    float4 a10 = *(const float4*)(qk + 32);
    float4 a11 = *(const float4*)(qk + 36);
    bf16x8 ah0, al0, ah1, al1;
    cvt8b(a00, a01, ah0, al0);
    cvt8b(a10, a11, ah1, al1);
#pragma unroll
    for (int nf = 0; nf < 4; ++nf) {
      int c = wn * 64 + nf * 16 + cb;
      int i0 = ((kt * 8 + kgl) * 128 + c) * 8;
      int i1 = ((kt * 8 + 4 + kgl) * 128 + c) * 8;
      bf16x8 bh0 = *(const bf16x8*)&Bsh[i0];
      bf16x8 bl0 = *(const bf16x8*)&Bsh[16384 + i0];
      bf16x8 bh1 = *(const bf16x8*)&Bsh[i1];
      bf16x8 bl1 = *(const bf16x8*)&Bsh[16384 + i1];
      acc[nf] = __builtin_amdgcn_mfma_f32_16x16x32_bf16(ah0, bh0, acc[nf], 0, 0, 0);
      acc[nf] = __builtin_amdgcn_mfma_f32_16x16x32_bf16(ah0, bl0, acc[nf], 0, 0, 0);
      acc[nf] = __builtin_amdgcn_mfma_f32_16x16x32_bf16(al0, bh0, acc[nf], 0, 0, 0);
      acc[nf] = __builtin_amdgcn_mfma_f32_16x16x32_bf16(ah1, bh1, acc[nf], 0, 0, 0);
      acc[nf] = __builtin_amdgcn_mfma_f32_16x16x32_bf16(ah1, bl1, acc[nf], 0, 0, 0);
      acc[nf] = __builtin_amdgcn_mfma_f32_16x16x32_bf16(al1, bh1, acc[nf], 0, 0, 0);
    }
  }

  const int l4 = lane >> 4;
#pragma unroll
  for (int nf = 0; nf < 4; ++nf)
#pragma unroll
    for (int r = 0; r < 4; ++r)
      out[(size_t)(row0 + wm * 16 + l4 * 4 + r) * 512 +
          col0 + wn * 64 + nf * 16 + cb] = acc[nf][r];
}

extern "C" void kernel_launch(void* const* d_in, const int* in_sizes, int n_in,
                              void* d_out, int out_size, void* d_ws, size_t ws_size,
                              hipStream_t stream) {
  (void)in_sizes; (void)n_in; (void)out_size; (void)ws_size;
  const float* x  = (const float*)d_in[0];
  const float* Wp = (const float*)d_in[1];
  const float* bp = (const float*)d_in[2];
  const float* W  = (const float*)d_in[3];
  // d_in[4] = n_routing (fixed = 3)
  char* ws = (char*)d_ws;
  float* p_ws = (float*)ws;                                   // 8 MB (p, then q in-place)
  unsigned short* th1 = (unsigned short*)(ws + 8388608);      // 256 KB
  unsigned short* tl1 = (unsigned short*)(ws + 8650752);      // 256 KB
  unsigned short* th2 = (unsigned short*)(ws + 8912896);      // 128 KB
  unsigned short* tl2 = (unsigned short*)(ws + 9043968);      // 128 KB
  float* Mws = (float*)(ws + 9175040);                        // 64 KB
  float* outp = (float*)d_out;

  caps_prep_all<<<96, 256, 0, stream>>>(Wp, W, th1, tl1, th2, tl2, Mws);
  caps_primary<<<512, 256, 0, stream>>>(x, th1, tl1, bp, p_ws);
  caps_route_g<<<256, 256, 0, stream>>>(p_ws, Mws, p_ws);
  caps_vout<<<dim3(256, 4), 512, 0, stream>>>(p_ws, th2, tl2, outp);
}

// Round 7
// 93.003 us; speedup vs baseline: 1.2917x; 1.2635x over previous
//
#include <hip/hip_runtime.h>
#include <hip/hip_bf16.h>
#include <math.h>

typedef __attribute__((ext_vector_type(8))) short bf16x8;
typedef __attribute__((ext_vector_type(8))) unsigned short u16x8;
typedef __attribute__((ext_vector_type(4))) float f32x4;

__device__ __forceinline__ unsigned short f2bf(float f) {
  unsigned u = __float_as_uint(f);
  return (unsigned short)((u + 0x7FFFu + ((u >> 16) & 1u)) >> 16);
}
__device__ __forceinline__ float bf2f(unsigned short h) {
  return __uint_as_float(((unsigned)h) << 16);
}
__device__ __forceinline__ void cvt8(const float4& a, const float4& b,
                                     u16x8& h, u16x8& l) {
  float f[8] = {a.x, a.y, a.z, a.w, b.x, b.y, b.z, b.w};
#pragma unroll
  for (int i = 0; i < 8; ++i) {
    unsigned short hh = f2bf(f[i]);
    h[i] = hh;
    l[i] = f2bf(f[i] - bf2f(hh));
  }
}
// fp32x8 -> bf16 hi/lo split via packed cvt (compiler emits v_cvt_pk_bf16_f32)
__device__ __forceinline__ void cvt8pk(const float4& a, const float4& b,
                                       u16x8& h, u16x8& l) {
  float f[8] = {a.x, a.y, a.z, a.w, b.x, b.y, b.z, b.w};
  unsigned* hp = (unsigned*)&h;
  unsigned* lp = (unsigned*)&l;
#pragma unroll
  for (int i = 0; i < 4; ++i) {
    __hip_bfloat162 hb = __float22bfloat162_rn(make_float2(f[2*i], f[2*i+1]));
    unsigned hv = *(unsigned*)&hb;
    hp[i] = hv;
    float r0 = f[2*i]     - __uint_as_float(hv << 16);
    float r1 = f[2*i + 1] - __uint_as_float(hv & 0xFFFF0000u);
    __hip_bfloat162 lb = __float22bfloat162_rn(make_float2(r0, r1));
    lp[i] = *(unsigned*)&lb;
  }
}
// cvt8b kept for caps_vout (bf16x8-typed)
__device__ __forceinline__ void cvt8b(const float4& a, const float4& b,
                                      bf16x8& h, bf16x8& l) {
  u16x8 hh, ll;
  cvt8pk(a, b, hh, ll);
  h = *(bf16x8*)&hh;
  l = *(bf16x8*)&ll;
}

#define GLD16(g, l) __builtin_amdgcn_global_load_lds( \
    (const __attribute__((address_space(1))) void*)(g), \
    (__attribute__((address_space(3))) void*)(l), 16, 0, 0)

// pair tables: 36 (m,n) pairs with m<=n
__device__ const int PM36[36] = {0,0,0,0,0,0,0,0, 1,1,1,1,1,1,1, 2,2,2,2,2,2,
                                 3,3,3,3,3, 4,4,4,4, 5,5,5, 6,6, 7};
__device__ const int PN36[36] = {0,1,2,3,4,5,6,7, 1,2,3,4,5,6,7, 2,3,4,5,6,7,
                                 3,4,5,6,7, 4,5,6,7, 5,6,7, 6,7, 7};
__device__ __forceinline__ constexpr int gidx(int a, int b) {
  int m = a < b ? a : b, n = a < b ? b : a;
  return m * 8 - (m * (m - 1)) / 2 + (n - m);
}

// ---------------------------------------------------------------------------
// K0 (merged): blocks 0-15: split/transpose Wp -> th1/tl1 [kt16][kg8][col128][e8]
//              blocks 16-31: split Wflat -> th2/tl2 [kt2][kg8][col512][e8]
//              blocks 32-95: Gram M[a][b] = Wf[a]·Wf[b]
// ---------------------------------------------------------------------------
__global__ __launch_bounds__(256) void caps_prep_all(
    const float* __restrict__ Wp, const float* __restrict__ W,
    unsigned short* __restrict__ th1, unsigned short* __restrict__ tl1,
    unsigned short* __restrict__ th2, unsigned short* __restrict__ tl2,
    float* __restrict__ M)
{
  __shared__ float tile[64][128];
  const int t = threadIdx.x, b = blockIdx.x;
  if (b < 16) {
    const float* src = Wp + (size_t)b * 64 * 128;
#pragma unroll
    for (int i = 0; i < 8; ++i) {
      int j = t + i * 256;
      int kk = j >> 5, q = j & 31;
      *(float4*)&tile[kk][q * 4] = *(const float4*)(src + kk * 128 + q * 4);
    }
    __syncthreads();
    const int col = t >> 1, kg0 = (t & 1) * 4;
    unsigned short hi[32], lo[32];
#pragma unroll
    for (int kk = 0; kk < 32; ++kk) {
      float v = tile[kg0 * 8 + kk][col];
      unsigned short h = f2bf(v);
      hi[kk] = h;
      lo[kk] = f2bf(v - bf2f(h));
    }
#pragma unroll
    for (int i = 0; i < 4; ++i) {
      size_t off = (size_t)b * 8192 + (size_t)(kg0 + i) * 1024 + (size_t)col * 8;
      u16x8 vh, vl;
#pragma unroll
      for (int e = 0; e < 8; ++e) { vh[e] = hi[i * 8 + e]; vl[e] = lo[i * 8 + e]; }
      *(u16x8*)(th1 + off) = vh;
      *(u16x8*)(tl1 + off) = vl;
    }
  } else if (b < 32) {
    int tt = (b - 16) * 256 + t;
#pragma unroll
    for (int h = 0; h < 2; ++h) {
      int c = tt + h * 4096;
      int kt = c >> 12, rem = c & 4095;
      int kg = rem >> 9, col = rem & 511;
      int kbase = kt * 64 + kg * 8;
      u16x8 vh, vl;
#pragma unroll
      for (int e = 0; e < 8; ++e) {
        float v = W[(size_t)(kbase + e) * 512 + col];
        unsigned short hh = f2bf(v);
        vh[e] = hh;
        vl[e] = f2bf(v - bf2f(hh));
      }
      size_t off = ((size_t)(kt * 8 + kg) * 512 + col) * 8;
      *(u16x8*)(th2 + off) = vh;
      *(u16x8*)(tl2 + off) = vl;
    }
  } else {
    int bb = b - 32;
    int a = (bb >> 3) * 16 + (t >> 4);
    int c = (bb & 7) * 16 + (t & 15);
    const float* wa = W + (size_t)a * 512;
    const float* wb = W + (size_t)c * 512;
    float acc = 0.f;
#pragma unroll 4
    for (int o = 0; o < 512; o += 4) {
      float4 xx = *(const float4*)(wa + o);
      float4 yy = *(const float4*)(wb + o);
      acc += xx.x * yy.x + xx.y * yy.y + xx.z * yy.z + xx.w * yy.w;
    }
    M[a * 128 + c] = acc;
  }
}

// ---------------------------------------------------------------------------
// K1: p = squash(x @ Wp + bp), split-bf16 MFMA.
// BM=32, BN=128, BK=64, 256 thr (4 waves = 2 rowg x 2 ch), grid 512
// -> 2 blocks/CU. LDS dbuf 2x40KB = 80KB:
//   per buf (shorts): A_hi[kg8][row32][e8] @0, A_lo @2048,
//                     B_hi[kg8][col128][e8] @4096, B_lo @12288.
// B staged via global_load_lds (pre-split, zero cvt); A reg-staged + pk-cvt.
// ---------------------------------------------------------------------------
#define K1BUF 20480   // shorts per buffer (40 KB)

__global__ __launch_bounds__(256) void caps_primary(
    const float* __restrict__ x, const unsigned short* __restrict__ bth,
    const unsigned short* __restrict__ btl, const float* __restrict__ bp,
    float* __restrict__ p_out)
{
  __shared__ unsigned short lds[2 * K1BUF];   // 80 KB
  const int tid  = threadIdx.x;
  const int lane = tid & 63;
  const int w    = tid >> 6;       // 0..3
  const int rowg = w >> 1;         // 0..1 -> rows rowg*16..+15
  const int ch   = w & 1;          // 0..1 -> cols ch*64..+63
  const int cb   = lane & 15;
  const int kgl  = lane >> 4;      // 0..3
  const int row0 = blockIdx.x * 32;

  const int rowA = tid & 31;       // A staging: (row=rowA, kg=kgA)
  const int kgA  = tid >> 5;       // 0..7
  const float* xrow = x + (size_t)(row0 + rowA) * 1024 + kgA * 8;

  f32x4 acc[4];
#pragma unroll
  for (int j = 0; j < 4; ++j) acc[j] = (f32x4){0.f, 0.f, 0.f, 0.f};

  float4 a0, a1;

#define A_LOAD(kt) do { const float* xp_ = xrow + (kt) * 64; \
    a0 = *(const float4*)(xp_); a1 = *(const float4*)(xp_ + 4); } while (0)

#define B_ISSUE(kt, bufi) do { \
    unsigned short* Bh_ = lds + (bufi) * K1BUF + 4096; \
    unsigned short* Bl_ = lds + (bufi) * K1BUF + 12288; \
    const unsigned short* gh_ = bth + ((size_t)(kt) * 1024 + tid) * 8; \
    const unsigned short* gl_ = btl + ((size_t)(kt) * 1024 + tid) * 8; \
    _Pragma("unroll") for (int c_ = 0; c_ < 4; ++c_) { \
      GLD16(gh_ + c_ * 2048, Bh_ + (c_ * 256 + tid) * 8); \
      GLD16(gl_ + c_ * 2048, Bl_ + (c_ * 256 + tid) * 8); \
    } } while (0)

#define A_WRITE(bufi) do { u16x8 h_, l_; cvt8pk(a0, a1, h_, l_); \
    unsigned short* A_ = lds + (bufi) * K1BUF; \
    *(u16x8*)(A_ + (kgA * 32 + rowA) * 8) = h_; \
    *(u16x8*)(A_ + 2048 + (kgA * 32 + rowA) * 8) = l_; } while (0)

#define COMPUTE(bufi) do { \
    const unsigned short* F = lds + (bufi) * K1BUF; \
    _Pragma("unroll") \
    for (int s = 0; s < 2; ++s) { \
      const int kg = s * 4 + kgl; \
      const int rA = rowg * 16 + cb; \
      const int cB = ch * 64 + cb; \
      bf16x8 ah = *(const bf16x8*)(F + (kg * 32 + rA) * 8); \
      bf16x8 al = *(const bf16x8*)(F + 2048 + (kg * 32 + rA) * 8); \
      _Pragma("unroll") \
      for (int nf = 0; nf < 4; ++nf) { \
        bf16x8 bh  = *(const bf16x8*)(F + 4096  + (kg * 128 + cB + nf * 16) * 8); \
        bf16x8 blo = *(const bf16x8*)(F + 12288 + (kg * 128 + cB + nf * 16) * 8); \
        acc[nf] = __builtin_amdgcn_mfma_f32_16x16x32_bf16(ah, bh,  acc[nf], 0, 0, 0); \
        acc[nf] = __builtin_amdgcn_mfma_f32_16x16x32_bf16(ah, blo, acc[nf], 0, 0, 0); \
        acc[nf] = __builtin_amdgcn_mfma_f32_16x16x32_bf16(al, bh,  acc[nf], 0, 0, 0); \
      } \
    } } while (0)

  // prologue
  A_LOAD(0);
  B_ISSUE(0, 0);
  A_WRITE(0);
  __syncthreads();

#pragma unroll 2
  for (int kt = 0; kt < 16; ++kt) {
    const int cur = kt & 1;
    if (kt < 15) {
      A_LOAD(kt + 1);          // global->reg (A), issued first
      B_ISSUE(kt + 1, cur ^ 1);// global->LDS async (B)
    }
    COMPUTE(cur);
    if (kt < 15) A_WRITE(cur ^ 1);
    __syncthreads();
  }
#undef A_LOAD
#undef B_ISSUE
#undef A_WRITE
#undef COMPUTE

  // epilogue: bias + per-capsule squash (capsule == one 16-wide n-frag)
  const int l4 = lane >> 4;
#pragma unroll
  for (int nf = 0; nf < 4; ++nf) {
    float bpv = bp[ch * 64 + nf * 16 + cb];
#pragma unroll
    for (int r = 0; r < 4; ++r) {
      float val = acc[nf][r] + bpv;
      float sq = val * val;
      sq += __shfl_xor(sq, 1); sq += __shfl_xor(sq, 2);
      sq += __shfl_xor(sq, 4); sq += __shfl_xor(sq, 8);
      float sc = (sq / (1.f + sq)) / sqrtf(sq + 1e-8f);
      p_out[(size_t)(row0 + rowg * 16 + l4 * 4 + r) * 128 +
            ch * 64 + nf * 16 + cb] = val * sc;
    }
  }
}

// ---------------------------------------------------------------------------
// K2: Gram-based routing (verified round 4, unchanged).
// ---------------------------------------------------------------------------
__global__ __launch_bounds__(256, 1) void caps_route_g(
    const float* __restrict__ p_in, const float* __restrict__ Mg,
    float* __restrict__ qout)
{
  __shared__ float p_lds[128 * 66];
  __shared__ float M_lds[16384];
  __shared__ float G_lds[64 * 37];
  __shared__ float cs_lds[64 * 9];
  const int tid  = threadIdx.x;
  const int lane = tid & 63;
  const int w    = tid >> 6;
  const int row0 = blockIdx.x * 64;

#pragma unroll
  for (int i = 0; i < 8; ++i) {
    int j = tid + i * 256;
    int r = j >> 5, c4 = j & 31;
    float4 v = *(const float4*)(p_in + (size_t)(row0 + r) * 128 + c4 * 4);
    p_lds[(c4 * 4 + 0) * 66 + r] = v.x;
    p_lds[(c4 * 4 + 1) * 66 + r] = v.y;
    p_lds[(c4 * 4 + 2) * 66 + r] = v.z;
    p_lds[(c4 * 4 + 3) * 66 + r] = v.w;
  }
#pragma unroll
  for (int i = 0; i < 16; ++i) {
    int j = tid + i * 256;
    *(float4*)&M_lds[j * 4] = *(const float4*)(Mg + j * 4);
  }
  __syncthreads();

  for (int i = 0; i < 9; ++i) {
    const int pi = w * 9 + i;
    const int m = PM36[pi], n = PN36[pi];
    float pm[16], pn[16];
#pragma unroll
    for (int j = 0; j < 16; ++j) pm[j] = p_lds[(m * 16 + j) * 66 + lane];
#pragma unroll
    for (int j = 0; j < 16; ++j) pn[j] = p_lds[(n * 16 + j) * 66 + lane];
    float acc = 0.f;
#pragma unroll
    for (int ii = 0; ii < 16; ++ii) {
      const float* Mr = &M_lds[(n * 16 + ii) * 128 + m * 16];
      float t = 0.f;
#pragma unroll
      for (int j4 = 0; j4 < 4; ++j4) {
        float4 mv = *(const float4*)(Mr + j4 * 4);
        t = fmaf(mv.x, pm[j4 * 4 + 0], t);
        t = fmaf(mv.y, pm[j4 * 4 + 1], t);
        t = fmaf(mv.z, pm[j4 * 4 + 2], t);
        t = fmaf(mv.w, pm[j4 * 4 + 3], t);
      }
      acc = fmaf(pn[ii], t, acc);
    }
    G_lds[lane * 37 + pi] = acc;
  }
  __syncthreads();

  if (w == 0) {
    float Gf[36];
#pragma unroll
    for (int j = 0; j < 36; ++j) Gf[j] = G_lds[lane * 37 + j];
    float bb[8] = {0.f, 0.f, 0.f, 0.f, 0.f, 0.f, 0.f, 0.f};
    float cs[8];
#pragma unroll
    for (int it = 0; it < 3; ++it) {
      float mx = bb[0];
#pragma unroll
      for (int n = 1; n < 8; ++n) mx = fmaxf(mx, bb[n]);
      float e[8], Z = 0.f;
#pragma unroll
      for (int n = 0; n < 8; ++n) { e[n] = expf(bb[n] - mx); Z += e[n]; }
      float inv = 1.f / Z;
      float c[8];
#pragma unroll
      for (int n = 0; n < 8; ++n) c[n] = e[n] * inv;
      float t[8] = {0.f, 0.f, 0.f, 0.f, 0.f, 0.f, 0.f, 0.f};
#pragma unroll
      for (int n = 0; n < 8; ++n)
#pragma unroll
        for (int m2 = 0; m2 < 8; ++m2)
          t[n] = fmaf(Gf[gidx(n, m2)], c[m2], t[n]);
      float ss = 0.f;
#pragma unroll
      for (int n = 0; n < 8; ++n) ss = fmaf(c[n], t[n], ss);
      float scale = (ss / (1.f + ss)) / sqrtf(ss + 1e-8f);
      if (it < 2) {
#pragma unroll
        for (int n = 0; n < 8; ++n) bb[n] += scale * t[n];
      } else {
#pragma unroll
        for (int n = 0; n < 8; ++n) cs[n] = scale * c[n];
      }
    }
#pragma unroll
    for (int n = 0; n < 8; ++n) cs_lds[lane * 9 + n] = cs[n];
  }
  __syncthreads();

#pragma unroll
  for (int i = 0; i < 8; ++i) {
    int j = tid + i * 256;
    int r = j >> 5, c4 = j & 31;
    float4 pv = *(const float4*)(p_in + (size_t)(row0 + r) * 128 + c4 * 4);
    float csv = cs_lds[r * 9 + (c4 >> 2)];
    *(float4*)(qout + (size_t)(row0 + r) * 128 + c4 * 4) =
        make_float4(pv.x * csv, pv.y * csv, pv.z * csv, pv.w * csv);
  }
}

// ---------------------------------------------------------------------------
// K3: v = q @ Wflat  [16384,128]x[128,512] split-bf16 MFMA.
// A register-direct from q; B staged ONCE to 64 KB LDS (1 barrier).
// Block 512 thr (8 waves: 4 wm x 2 wn), BM=64, BN=128, grid (256,4).
// ---------------------------------------------------------------------------
__global__ __launch_bounds__(512) void caps_vout(
    const float* __restrict__ q, const unsigned short* __restrict__ bth,
    const unsigned short* __restrict__ btl, float* __restrict__ out)
{
  __shared__ unsigned short Bsh[32768];   // hi @0, lo @16384 (ushorts)
  const int tid  = threadIdx.x;
  const int lane = tid & 63;
  const int w    = tid >> 6;
  const int wm   = w >> 1;
  const int wn   = w & 1;
  const int row0 = blockIdx.x * 64;
  const int col0 = blockIdx.y * 128;

  // stage both K-tiles of B for this col-slab: [kt2][kg8][128col][e8]
#pragma unroll
  for (int i = 0; i < 4; ++i) {
    int idx = tid + i * 512;               // 2048 chunks
    int kt = idx >> 10, kg = (idx >> 7) & 7, col = idx & 127;
    size_t g = ((size_t)(kt * 8 + kg) * 512 + col0 + col) * 8;
    *(u16x8*)&Bsh[idx * 8] = *(const u16x8*)(bth + g);
    *(u16x8*)&Bsh[16384 + idx * 8] = *(const u16x8*)(btl + g);
  }
  __syncthreads();

  const int cb = lane & 15, kgl = lane >> 4;
  const int rA = row0 + wm * 16 + cb;
  const float* qp = q + (size_t)rA * 128;

  f32x4 acc[4];
#pragma unroll
  for (int j = 0; j < 4; ++j) acc[j] = (f32x4){0.f, 0.f, 0.f, 0.f};

#pragma unroll
  for (int kt = 0; kt < 2; ++kt) {
    const float* qk = qp + kt * 64 + kgl * 8;
    float4 a00 = *(const float4*)(qk);
    float4 a01 = *(const float4*)(qk + 4);
    float4 a10 = *(const float4*)(qk + 32);
    float4 a11 = *(const float4*)(qk + 36);
    bf16x8 ah0, al0, ah1, al1;
    cvt8b(a00, a01, ah0, al0);
    cvt8b(a10, a11, ah1, al1);
#pragma unroll
    for (int nf = 0; nf < 4; ++nf) {
      int c = wn * 64 + nf * 16 + cb;
      int i0 = ((kt * 8 + kgl) * 128 + c) * 8;
      int i1 = ((kt * 8 + 4 + kgl) * 128 + c) * 8;
      bf16x8 bh0 = *(const bf16x8*)&Bsh[i0];
      bf16x8 bl0 = *(const bf16x8*)&Bsh[16384 + i0];
      bf16x8 bh1 = *(const bf16x8*)&Bsh[i1];
      bf16x8 bl1 = *(const bf16x8*)&Bsh[16384 + i1];
      acc[nf] = __builtin_amdgcn_mfma_f32_16x16x32_bf16(ah0, bh0, acc[nf], 0, 0, 0);
      acc[nf] = __builtin_amdgcn_mfma_f32_16x16x32_bf16(ah0, bl0, acc[nf], 0, 0, 0);
      acc[nf] = __builtin_amdgcn_mfma_f32_16x16x32_bf16(al0, bh0, acc[nf], 0, 0, 0);
      acc[nf] = __builtin_amdgcn_mfma_f32_16x16x32_bf16(ah1, bh1, acc[nf], 0, 0, 0);
      acc[nf] = __builtin_amdgcn_mfma_f32_16x16x32_bf16(ah1, bl1, acc[nf], 0, 0, 0);
      acc[nf] = __builtin_amdgcn_mfma_f32_16x16x32_bf16(al1, bh1, acc[nf], 0, 0, 0);
    }
  }

  const int l4 = lane >> 4;
#pragma unroll
  for (int nf = 0; nf < 4; ++nf)
#pragma unroll
    for (int r = 0; r < 4; ++r)
      out[(size_t)(row0 + wm * 16 + l4 * 4 + r) * 512 +
          col0 + wn * 64 + nf * 16 + cb] = acc[nf][r];
}

extern "C" void kernel_launch(void* const* d_in, const int* in_sizes, int n_in,
                              void* d_out, int out_size, void* d_ws, size_t ws_size,
                              hipStream_t stream) {
  (void)in_sizes; (void)n_in; (void)out_size; (void)ws_size;
  const float* x  = (const float*)d_in[0];
  const float* Wp = (const float*)d_in[1];
  const float* bp = (const float*)d_in[2];
  const float* W  = (const float*)d_in[3];
  // d_in[4] = n_routing (fixed = 3)
  char* ws = (char*)d_ws;
  float* p_ws = (float*)ws;                                   // 8 MB (p, then q in-place)
  unsigned short* th1 = (unsigned short*)(ws + 8388608);      // 256 KB
  unsigned short* tl1 = (unsigned short*)(ws + 8650752);      // 256 KB
  unsigned short* th2 = (unsigned short*)(ws + 8912896);      // 128 KB
  unsigned short* tl2 = (unsigned short*)(ws + 9043968);      // 128 KB
  float* Mws = (float*)(ws + 9175040);                        // 64 KB
  float* outp = (float*)d_out;

  caps_prep_all<<<96, 256, 0, stream>>>(Wp, W, th1, tl1, th2, tl2, Mws);
  caps_primary<<<512, 256, 0, stream>>>(x, th1, tl1, bp, p_ws);
  caps_route_g<<<256, 256, 0, stream>>>(p_ws, Mws, p_ws);
  caps_vout<<<dim3(256, 4), 512, 0, stream>>>(p_ws, th2, tl2, outp);
}